// Round 1
// baseline (1537.538 us; speedup 1.0000x reference)
//
#include <hip/hip_runtime.h>
#include <hip/hip_bf16.h>
#include <stdint.h>

#define NTOK 16384
#define DM   2048
#define NE   8

typedef __bf16 bf16x8 __attribute__((ext_vector_type(8)));
typedef float f32x4 __attribute__((ext_vector_type(4)));
typedef unsigned short ushort_t;

// RNE float -> bf16 (matches numpy/jax rounding; inputs finite)
__device__ __forceinline__ ushort_t f2bf(float f) {
  uint32_t u = __builtin_bit_cast(uint32_t, f);
  u = (u + 0x7FFFu + ((u >> 16) & 1u)) >> 16;
  return (ushort_t)u;
}

// ---------------- convert W and hs to bf16 ----------------
__global__ void convert_kernel(const float* __restrict__ W, const float* __restrict__ hs,
                               ushort_t* __restrict__ Wb, ushort_t* __restrict__ hsb) {
  const long NW4 = (long)NE * DM * DM / 4;   // 8388608
  const long NH4 = (long)NTOK * DM / 4;      // 8388608
  long i = (long)blockIdx.x * blockDim.x + threadIdx.x;
  if (i < NW4) {
    float4 v = ((const float4*)W)[i];
    ushort4 o = make_ushort4(f2bf(v.x), f2bf(v.y), f2bf(v.z), f2bf(v.w));
    ((ushort4*)Wb)[i] = o;
  } else {
    long j = i - NW4;
    if (j < NH4) {
      float4 v = ((const float4*)hs)[j];
      ushort4 o = make_ushort4(f2bf(v.x), f2bf(v.y), f2bf(v.z), f2bf(v.w));
      ((ushort4*)hsb)[j] = o;
    }
  }
}

// ---------------- router: one wave per token, fp64 accumulation ----------------
__global__ void router_kernel(const float* __restrict__ hs, const float* __restrict__ Wg,
                              const float* __restrict__ bg, int* __restrict__ cnt,
                              int* __restrict__ pairs) {
  int token = (blockIdx.x * blockDim.x + threadIdx.x) >> 6;
  int lane = threadIdx.x & 63;
  if (token >= NTOK) return;
  const float* hrow = hs + (size_t)token * DM;
  double acc[NE] = {0,0,0,0,0,0,0,0};
  for (int k = lane; k < DM; k += 64) {
    double h = (double)hrow[k];
#pragma unroll
    for (int e = 0; e < NE; e++) acc[e] += h * (double)Wg[e * DM + k];
  }
#pragma unroll
  for (int off = 32; off > 0; off >>= 1) {
#pragma unroll
    for (int e = 0; e < NE; e++) acc[e] += __shfl_down(acc[e], off, 64);
  }
  if (lane == 0) {
    double lg[NE];
#pragma unroll
    for (int e = 0; e < NE; e++) lg[e] = acc[e] + (double)bg[e];
    int e1 = 0; double m1 = lg[0];
#pragma unroll
    for (int e = 1; e < NE; e++) if (lg[e] > m1) { m1 = lg[e]; e1 = e; }  // strict > : lower idx wins ties (top_k semantics)
    int e2 = -1; double m2 = -1e300;
#pragma unroll
    for (int e = 0; e < NE; e++) if (e != e1 && lg[e] > m2) { m2 = lg[e]; e2 = e; }
    pairs[token] = e1 | (e2 << 4);
    atomicAdd(&cnt[e1], 1);
    atomicAdd(&cnt[e2], 1);
  }
}

// ---------------- scan: offsets + tile starts ----------------
__global__ void scan_kernel(const int* __restrict__ cnt, int* __restrict__ offsets,
                            int* __restrict__ tile_starts) {
  if (threadIdx.x == 0 && blockIdx.x == 0) {
    int o = 0, ts = 0;
    for (int e = 0; e < NE; e++) {
      offsets[e] = o;
      tile_starts[e] = ts;
      o += cnt[e];
      ts += (cnt[e] + 127) >> 7;
    }
    offsets[NE] = o;
    tile_starts[NE] = ts;
  }
}

// ---------------- scatter tokens into per-expert lists ----------------
__global__ void scatter_kernel(const int* __restrict__ pairs, const int* __restrict__ offsets,
                               int* __restrict__ fill, int* __restrict__ token_list) {
  int t = blockIdx.x * blockDim.x + threadIdx.x;
  if (t >= NTOK) return;
  int p = pairs[t];
  int e1 = p & 15, e2 = p >> 4;
  int pos = atomicAdd(&fill[e1], 1);
  token_list[offsets[e1] + pos] = t;
  pos = atomicAdd(&fill[e2], 1);
  token_list[offsets[e2] + pos] = t;
}

// ---------------- grouped GEMM: out[tok] += hs[tok] @ W[e]^T + b[e] ----------------
// 128x128 tile, BK=64, 4 waves, each wave = 64x64 quadrant = 4x4 MFMA 16x16x32 tiles.
// LDS row stride 72 elem (144 B): 16B-aligned b128 reads, <=2-way bank conflicts.
#define LDT 72
__global__ __launch_bounds__(256, 2) void moe_gemm(
    const ushort_t* __restrict__ hsb, const ushort_t* __restrict__ Wb,
    const float* __restrict__ bias, const int* __restrict__ token_list,
    const int* __restrict__ offsets, const int* __restrict__ tile_starts,
    float* __restrict__ out)
{
  __shared__ ushort_t Als[128 * LDT];
  __shared__ ushort_t Bls[128 * LDT];
  __shared__ int toks[128];

  const int ntile = blockIdx.x & 15;
  const int btile = blockIdx.x >> 4;
  if (btile >= tile_starts[NE]) return;
  int e = 0;
#pragma unroll
  for (int q = 1; q < NE; q++) if (btile >= tile_starts[q]) e = q;
  const int mtile = btile - tile_starts[e];
  const int off = offsets[e];
  const int ne = offsets[e + 1] - off;
  const int m0 = mtile * 128;

  const int tid = threadIdx.x;
  if (tid < 128) {
    int r = m0 + tid;
    toks[tid] = (r < ne) ? token_list[off + r] : -1;
  }
  __syncthreads();

  const int lane = tid & 63;
  const int wave = tid >> 6;
  const int wm = (wave >> 1) << 6;
  const int wn = (wave & 1) << 6;
  const int lrow = lane & 15;
  const int lk = (lane >> 4) << 3;

  f32x4 acc[4][4] = {};

  const ushort_t* We = Wb + (size_t)e * DM * DM;
  const int ar = tid >> 3;        // 0..31 (row within 32-row pass)
  const int ac = (tid & 7) << 3;  // bf16 col 0..56 step 8

  for (int k0 = 0; k0 < DM; k0 += 64) {
    // stage A (gathered token rows) and B (weight rows), 8 bf16 per thread per pass
#pragma unroll
    for (int p = 0; p < 4; p++) {
      int r = ar + p * 32;
      int tok = toks[r];
      uint4 av = make_uint4(0, 0, 0, 0);
      if (tok >= 0) av = *(const uint4*)(hsb + (size_t)tok * DM + k0 + ac);
      *(uint4*)(&Als[r * LDT + ac]) = av;
      uint4 bv = *(const uint4*)(We + (size_t)(ntile * 128 + r) * DM + k0 + ac);
      *(uint4*)(&Bls[r * LDT + ac]) = bv;
    }
    __syncthreads();
#pragma unroll
    for (int kk = 0; kk < 64; kk += 32) {
      bf16x8 af[4], bfr[4];
#pragma unroll
      for (int i = 0; i < 4; i++)
        af[i] = *(const bf16x8*)(&Als[(wm + i * 16 + lrow) * LDT + kk + lk]);
#pragma unroll
      for (int j = 0; j < 4; j++)
        bfr[j] = *(const bf16x8*)(&Bls[(wn + j * 16 + lrow) * LDT + kk + lk]);
#pragma unroll
      for (int i = 0; i < 4; i++)
#pragma unroll
        for (int j = 0; j < 4; j++)
          acc[i][j] = __builtin_amdgcn_mfma_f32_16x16x32_bf16(af[i], bfr[j], acc[i][j], 0, 0, 0);
    }
    __syncthreads();
  }

  // epilogue: C/D layout col=lane&15, row=(lane>>4)*4+reg; fuse per-expert bias; atomic combine
#pragma unroll
  for (int j = 0; j < 4; j++) {
    const int col = ntile * 128 + wn + j * 16 + lrow;
    const float bv = bias[e * DM + col];
#pragma unroll
    for (int i = 0; i < 4; i++) {
      const int rbase = wm + i * 16 + ((lane >> 4) << 2);
#pragma unroll
      for (int r = 0; r < 4; r++) {
        int tok = toks[rbase + r];
        if (tok >= 0) atomicAdd(out + (size_t)tok * DM + col, acc[i][j][r] + bv);
      }
    }
  }
}

extern "C" void kernel_launch(void* const* d_in, const int* in_sizes, int n_in,
                              void* d_out, int out_size, void* d_ws, size_t ws_size,
                              hipStream_t stream) {
  const float* hs = (const float*)d_in[0];
  const float* Wg = (const float*)d_in[1];
  const float* bg = (const float*)d_in[2];
  const float* W  = (const float*)d_in[3];
  const float* b  = (const float*)d_in[4];
  float* out = (float*)d_out;

  char* ws = (char*)d_ws;
  int* cnt         = (int*)(ws + 0);     // 8 ints
  int* fill        = (int*)(ws + 64);    // 8 ints
  int* offsets     = (int*)(ws + 128);   // 9 ints
  int* tile_starts = (int*)(ws + 192);   // 9 ints
  int* pairs       = (int*)(ws + 256);                 // 16384 ints
  int* token_list  = (int*)(ws + 256 + 65536);         // 32768 ints
  ushort_t* Wb  = (ushort_t*)(ws + 196864);            // 8*2048*2048 bf16 = 64 MiB
  ushort_t* hsb = (ushort_t*)(ws + 196864 + 67108864); // 16384*2048 bf16 = 64 MiB

  hipMemsetAsync(d_ws, 0, 256, stream);                                  // cnt + fill
  hipMemsetAsync(d_out, 0, (size_t)NTOK * DM * sizeof(float), stream);   // atomic combine target

  convert_kernel<<<65536, 256, 0, stream>>>(W, hs, Wb, hsb);
  router_kernel<<<4096, 256, 0, stream>>>(hs, Wg, bg, cnt, pairs);
  scan_kernel<<<1, 64, 0, stream>>>(cnt, offsets, tile_starts);
  scatter_kernel<<<64, 256, 0, stream>>>(pairs, offsets, fill, token_list);
  // max tiles: sum ceil(n_e/128) <= 16384*2/128 + 8 = 264; grid = 264 * 16 N-tiles
  moe_gemm<<<264 * 16, 256, 0, stream>>>(hsb, Wb, b, token_list, offsets, tile_starts, out);
}

// Round 3
// 977.816 us; speedup vs baseline: 1.5724x; 1.5724x over previous
//
#include <hip/hip_runtime.h>
#include <hip/hip_bf16.h>
#include <stdint.h>

#define NTOK 16384
#define DM   2048
#define NE   8
#define KTOT (2 * DM)   // pair-grouped: K = 4096
#define MAXT 192        // max m-tiles: 16384/128 + 28 pairs = 156; padded

typedef __bf16 bf16x8 __attribute__((ext_vector_type(8)));
typedef float f32x4 __attribute__((ext_vector_type(4)));
typedef unsigned short ushort_t;

typedef __attribute__((address_space(3))) void lds_void;
typedef __attribute__((address_space(1))) void g_void;
#define GLOAD_LDS16(g, l) \
  __builtin_amdgcn_global_load_lds((g_void*)(void*)(g), (lds_void*)(l), 16, 0, 0)

// RNE float -> bf16
__device__ __forceinline__ ushort_t f2bf(float f) {
  uint32_t u = __builtin_bit_cast(uint32_t, f);
  u = (u + 0x7FFFu + ((u >> 16) & 1u)) >> 16;
  return (ushort_t)u;
}

// ---------------- convert W to bf16 (hs converted inside router) ----------------
__global__ void convert_w_kernel(const float* __restrict__ W, ushort_t* __restrict__ Wb) {
  long i = (long)blockIdx.x * blockDim.x + threadIdx.x;   // 8.39M float4 items
  float4 v = ((const float4*)W)[i];
  ((ushort4*)Wb)[i] = make_ushort4(f2bf(v.x), f2bf(v.y), f2bf(v.z), f2bf(v.w));
}

// ---------------- router: one wave/token, fp64 accum; also emits hsb ----------------
__global__ void router_kernel(const float* __restrict__ hs, const float* __restrict__ Wg,
                              const float* __restrict__ bg, int* __restrict__ pair_cnt,
                              int* __restrict__ pairs, ushort_t* __restrict__ hsb) {
  int token = (blockIdx.x * blockDim.x + threadIdx.x) >> 6;
  int lane = threadIdx.x & 63;
  if (token >= NTOK) return;
  const float4* h4 = (const float4*)(hs + (size_t)token * DM);
  const float4* w4 = (const float4*)Wg;
  ushort4* o4 = (ushort4*)(hsb + (size_t)token * DM);
  double acc[NE] = {};
#pragma unroll
  for (int j = 0; j < 8; j++) {
    int c = lane + 64 * j;
    float4 h = h4[c];
    o4[c] = make_ushort4(f2bf(h.x), f2bf(h.y), f2bf(h.z), f2bf(h.w));
#pragma unroll
    for (int e = 0; e < NE; e++) {
      float4 w = w4[e * (DM / 4) + c];
      acc[e] += (double)h.x * w.x + (double)h.y * w.y + (double)h.z * w.z + (double)h.w * w.w;
    }
  }
#pragma unroll
  for (int off = 32; off > 0; off >>= 1)
#pragma unroll
    for (int e = 0; e < NE; e++) acc[e] += __shfl_down(acc[e], off, 64);
  if (lane == 0) {
    double lg[NE];
#pragma unroll
    for (int e = 0; e < NE; e++) lg[e] = acc[e] + (double)bg[e];
    int e1 = 0; double m1 = lg[0];
#pragma unroll
    for (int e = 1; e < NE; e++) if (lg[e] > m1) { m1 = lg[e]; e1 = e; }  // strict >: lower idx wins ties
    int e2 = -1; double m2 = -1e300;
#pragma unroll
    for (int e = 0; e < NE; e++) if (e != e1 && lg[e] > m2) { m2 = lg[e]; e2 = e; }
    int lo = min(e1, e2), hi = max(e1, e2);
    int pid = lo * NE + hi;           // unordered pair id (order irrelevant: unweighted sum)
    pairs[token] = pid;
    atomicAdd(&pair_cnt[pid], 1);
  }
}

// ---------------- scan: one wave, shuffle prefix sums over 64 pair slots ----------------
__global__ void scan_kernel(const int* __restrict__ pair_cnt, int* __restrict__ meta,
                            int* __restrict__ pair_off, int* __restrict__ tile_pid,
                            int* __restrict__ tile_tokoff, int* __restrict__ tile_nrows) {
  int lane = threadIdx.x;   // 64 threads = 1 wave
  int c = pair_cnt[lane];
  int off = c;
#pragma unroll
  for (int d = 1; d < 64; d <<= 1) { int t = __shfl_up(off, d, 64); if (lane >= d) off += t; }
  off -= c;                 // exclusive token offset for this pid
  pair_off[lane] = off;
  int nt = (c + 127) >> 7;
  int toff = nt;
#pragma unroll
  for (int d = 1; d < 64; d <<= 1) { int t = __shfl_up(toff, d, 64); if (lane >= d) toff += t; }
  toff -= nt;               // exclusive tile offset
  for (int m = 0; m < nt; m++) {
    tile_pid[toff + m] = lane;
    tile_tokoff[toff + m] = off + m * 128;
    tile_nrows[toff + m] = min(c - m * 128, 128);
  }
  if (lane == 63) meta[0] = toff + nt;   // total tiles
}

// ---------------- scatter tokens into pair-group lists ----------------
__global__ void scatter_kernel(const int* __restrict__ pairs, const int* __restrict__ pair_off,
                               int* __restrict__ pair_fill, int* __restrict__ token_list) {
  int t = blockIdx.x * blockDim.x + threadIdx.x;
  if (t >= NTOK) return;
  int pid = pairs[t];
  int pos = atomicAdd(&pair_fill[pid], 1);
  token_list[pair_off[pid] + pos] = t;
}

// ---------------- grouped GEMM over expert pairs ----------------
// Block tile 128(tokens) x 128(cols), K = 4096 (= W[e1] cols then W[e2] cols, both halves
// reading the SAME hs cols 0..2047), BK = 64. 4 waves, each a 64x64 quadrant of 4x4 mfma
// 16x16x32. LDS layout is fragment-major: 16 chunks of 1024B per operand; chunk (mi,ki)
// holds the 16x32 MFMA tile in lane order (lane L's 16B at chunk + L*16) ->
// global_load_lds direct, ds_read_b128 at base+lane*16 is conflict-free.
__global__ __launch_bounds__(256, 3) void moe_gemm(
    const ushort_t* __restrict__ hsb, const ushort_t* __restrict__ Wb,
    const float* __restrict__ bias, const int* __restrict__ token_list,
    const int* __restrict__ meta, const int* __restrict__ tile_pid,
    const int* __restrict__ tile_tokoff, const int* __restrict__ tile_nrows,
    float* __restrict__ out)
{
  __shared__ ushort_t Als[16 * 512];   // 16 KB
  __shared__ ushort_t Bls[16 * 512];   // 16 KB
  __shared__ int toks[128];

  const int ntile = blockIdx.x & 15;
  const int btile = blockIdx.x >> 4;
  if (btile >= meta[0]) return;
  const int pid = tile_pid[btile];
  const int e1 = pid >> 3, e2 = pid & 7;
  const int tokoff = tile_tokoff[btile];
  const int nrows = tile_nrows[btile];
  const int n0 = ntile * 128;

  const int tid = threadIdx.x;
  if (tid < 128) toks[tid] = (tid < nrows) ? token_list[tokoff + tid] : -1;
  __syncthreads();

  const int lane = tid & 63;
  const int wave = tid >> 6;
  const int l15 = lane & 15;
  const int lhi = lane >> 4;     // 0..3

  // wave w stages A chunks mi={2w,2w+1} and B chunks nj={2w,2w+1}
  const int tokr0 = toks[32 * wave + l15];
  const int tokr1 = toks[32 * wave + 16 + l15];
  const ushort_t* aA0 = hsb + (size_t)(tokr0 < 0 ? 0 : tokr0) * DM + lhi * 8;  // pad rows -> row 0 (stores skipped)
  const ushort_t* aA1 = hsb + (size_t)(tokr1 < 0 ? 0 : tokr1) * DM + lhi * 8;
  const size_t brow0 = (size_t)(n0 + 32 * wave + l15) * DM + lhi * 8;
  const size_t brow1 = brow0 + (size_t)16 * DM;

  ushort_t* als = Als + wave * 2048;   // chunk (2w,0) base, elements
  ushort_t* bls = Bls + wave * 2048;

  f32x4 acc[4][4] = {};
  const size_t wstride = (size_t)DM * DM;

  for (int k0 = 0; k0 < KTOT; k0 += 64) {
    // BK=64 lies entirely within one expert's K half (2048 % 64 == 0).
    // BOTH the A and B k-offsets wrap at DM: A is logically [hs | hs] over K=4096.
    const int ka = k0 & (DM - 1);
    const ushort_t* wbase = Wb + (size_t)(k0 < DM ? e1 : e2) * wstride + ka;
    GLOAD_LDS16(aA0 + ka,        als);
    GLOAD_LDS16(aA0 + ka + 32,   als + 512);
    GLOAD_LDS16(aA1 + ka,        als + 1024);
    GLOAD_LDS16(aA1 + ka + 32,   als + 1536);
    GLOAD_LDS16(wbase + brow0,      bls);
    GLOAD_LDS16(wbase + brow0 + 32, bls + 512);
    GLOAD_LDS16(wbase + brow1,      bls + 1024);
    GLOAD_LDS16(wbase + brow1 + 32, bls + 1536);
    __syncthreads();
#pragma unroll
    for (int kk = 0; kk < 2; kk++) {
      bf16x8 af[4], bfr[4];
#pragma unroll
      for (int i = 0; i < 4; i++)
        af[i] = *(const bf16x8*)(&Als[(((wave >> 1) * 4 + i) * 2 + kk) * 512 + lane * 8]);
#pragma unroll
      for (int j = 0; j < 4; j++)
        bfr[j] = *(const bf16x8*)(&Bls[(((wave & 1) * 4 + j) * 2 + kk) * 512 + lane * 8]);
#pragma unroll
      for (int i = 0; i < 4; i++)
#pragma unroll
        for (int j = 0; j < 4; j++)
          acc[i][j] = __builtin_amdgcn_mfma_f32_16x16x32_bf16(af[i], bfr[j], acc[i][j], 0, 0, 0);
    }
    __syncthreads();
  }

  // epilogue: C/D layout col=lane&15, row=(lane>>4)*4+reg; one writer per output row -> plain stores
  const int wm = (wave >> 1) * 64;
  const int wn = (wave & 1) * 64;
#pragma unroll
  for (int j = 0; j < 4; j++) {
    const int col = n0 + wn + j * 16 + l15;
    const float bsum = bias[e1 * DM + col] + bias[e2 * DM + col];
#pragma unroll
    for (int i = 0; i < 4; i++) {
      const int rbase = wm + i * 16 + lhi * 4;
#pragma unroll
      for (int r = 0; r < 4; r++) {
        const int tok = toks[rbase + r];
        if (tok >= 0) out[(size_t)tok * DM + col] = acc[i][j][r] + bsum;
      }
    }
  }
}

extern "C" void kernel_launch(void* const* d_in, const int* in_sizes, int n_in,
                              void* d_out, int out_size, void* d_ws, size_t ws_size,
                              hipStream_t stream) {
  const float* hs = (const float*)d_in[0];
  const float* Wg = (const float*)d_in[1];
  const float* bg = (const float*)d_in[2];
  const float* W  = (const float*)d_in[3];
  const float* b  = (const float*)d_in[4];
  float* out = (float*)d_out;

  char* ws = (char*)d_ws;
  int* pair_cnt    = (int*)(ws + 0);      // 64 ints
  int* pair_fill   = (int*)(ws + 256);    // 64 ints
  int* meta        = (int*)(ws + 512);    // 16 ints
  int* pair_off    = (int*)(ws + 576);    // 64 ints
  int* tile_pid    = (int*)(ws + 832);    // MAXT
  int* tile_tokoff = (int*)(ws + 1600);   // MAXT
  int* tile_nrows  = (int*)(ws + 2368);   // MAXT
  int* pairs       = (int*)(ws + 3136);   // 16384
  int* token_list  = (int*)(ws + 68672);  // 16384
  ushort_t* Wb  = (ushort_t*)(ws + 134400);              // 64 MiB
  ushort_t* hsb = (ushort_t*)(ws + 134400 + 67108864);   // 64 MiB

  hipMemsetAsync(d_ws, 0, 576, stream);   // pair_cnt + pair_fill + meta

  convert_w_kernel<<<(NE * DM * DM / 4) / 256, 256, 0, stream>>>(W, Wb);
  router_kernel<<<NTOK / 4, 256, 0, stream>>>(hs, Wg, bg, pair_cnt, pairs, hsb);
  scan_kernel<<<1, 64, 0, stream>>>(pair_cnt, meta, pair_off, tile_pid, tile_tokoff, tile_nrows);
  scatter_kernel<<<NTOK / 256, 256, 0, stream>>>(pairs, pair_off, pair_fill, token_list);
  moe_gemm<<<MAXT * 16, 256, 0, stream>>>(hsb, Wb, b, token_list, meta,
                                          tile_pid, tile_tokoff, tile_nrows, out);
}

// Round 4
// 962.704 us; speedup vs baseline: 1.5971x; 1.0157x over previous
//
#include <hip/hip_runtime.h>
#include <hip/hip_bf16.h>
#include <stdint.h>

#define NTOK 16384
#define DM   2048
#define NE   8
#define KTOT (2 * DM)   // pair-grouped: K = 4096
#define MAXT 160        // max m-tiles: 16384/128 + 28 pairs = 156; padded
#define NT   8          // 8 ntiles of 256 cols

typedef __bf16 bf16x8 __attribute__((ext_vector_type(8)));
typedef float f32x4 __attribute__((ext_vector_type(4)));
typedef unsigned short ushort_t;

typedef __attribute__((address_space(3))) void lds_void;
typedef __attribute__((address_space(1))) void g_void;
#define GLOAD_LDS16(g, l) \
  __builtin_amdgcn_global_load_lds((g_void*)(void*)(g), (lds_void*)(l), 16, 0, 0)

// RNE float -> bf16
__device__ __forceinline__ ushort_t f2bf(float f) {
  uint32_t u = __builtin_bit_cast(uint32_t, f);
  u = (u + 0x7FFFu + ((u >> 16) & 1u)) >> 16;
  return (ushort_t)u;
}

// ---------------- fused prep: W->bf16 convert (blocks 0..8191) + router (blocks 8192..12287) ----
__global__ void prep_kernel(const float* __restrict__ W, ushort_t* __restrict__ Wb,
                            const float* __restrict__ hs, const float* __restrict__ Wg,
                            const float* __restrict__ bg, int* __restrict__ pair_cnt,
                            int* __restrict__ pairs, ushort_t* __restrict__ hsb) {
  if (blockIdx.x < 8192) {
    // convert W: 8.39M float4 items, 4 per thread
    long i0 = ((long)blockIdx.x * 256 + threadIdx.x) * 4;
#pragma unroll
    for (int u = 0; u < 4; u++) {
      long i = i0 + u;
      float4 v = ((const float4*)W)[i];
      ((ushort4*)Wb)[i] = make_ushort4(f2bf(v.x), f2bf(v.y), f2bf(v.z), f2bf(v.w));
    }
    return;
  }
  // router: one wave per token, fp64 accum; also emits hsb (bf16 hs, token order)
  int token = (((int)blockIdx.x - 8192) * 256 + (int)threadIdx.x) >> 6;
  int lane = threadIdx.x & 63;
  if (token >= NTOK) return;
  const float4* h4 = (const float4*)(hs + (size_t)token * DM);
  const float4* w4 = (const float4*)Wg;
  ushort4* o4 = (ushort4*)(hsb + (size_t)token * DM);
  double acc[NE] = {};
#pragma unroll
  for (int j = 0; j < 8; j++) {
    int c = lane + 64 * j;
    float4 h = h4[c];
    o4[c] = make_ushort4(f2bf(h.x), f2bf(h.y), f2bf(h.z), f2bf(h.w));
#pragma unroll
    for (int e = 0; e < NE; e++) {
      float4 w = w4[e * (DM / 4) + c];
      acc[e] += (double)h.x * w.x + (double)h.y * w.y + (double)h.z * w.z + (double)h.w * w.w;
    }
  }
#pragma unroll
  for (int off = 32; off > 0; off >>= 1)
#pragma unroll
    for (int e = 0; e < NE; e++) acc[e] += __shfl_down(acc[e], off, 64);
  if (lane == 0) {
    double lg[NE];
#pragma unroll
    for (int e = 0; e < NE; e++) lg[e] = acc[e] + (double)bg[e];
    int e1 = 0; double m1 = lg[0];
#pragma unroll
    for (int e = 1; e < NE; e++) if (lg[e] > m1) { m1 = lg[e]; e1 = e; }  // strict >: lower idx wins ties
    int e2 = -1; double m2 = -1e300;
#pragma unroll
    for (int e = 0; e < NE; e++) if (e != e1 && lg[e] > m2) { m2 = lg[e]; e2 = e; }
    int lo = min(e1, e2), hi = max(e1, e2);
    pairs[token] = lo * NE + hi;      // unordered pair id (order irrelevant: unweighted sum)
    atomicAdd(&pair_cnt[lo * NE + hi], 1);
  }
}

// ---------------- scan: one wave, shuffle prefix sums over 64 pair slots ----------------
__global__ void scan_kernel(const int* __restrict__ pair_cnt, int* __restrict__ meta,
                            int* __restrict__ pair_off, int* __restrict__ tile_pid,
                            int* __restrict__ tile_tokoff, int* __restrict__ tile_nrows) {
  int lane = threadIdx.x;   // 64 threads = 1 wave
  int c = pair_cnt[lane];
  int off = c;
#pragma unroll
  for (int d = 1; d < 64; d <<= 1) { int t = __shfl_up(off, d, 64); if (lane >= d) off += t; }
  off -= c;
  pair_off[lane] = off;
  int nt = (c + 127) >> 7;
  int toff = nt;
#pragma unroll
  for (int d = 1; d < 64; d <<= 1) { int t = __shfl_up(toff, d, 64); if (lane >= d) toff += t; }
  toff -= nt;
  for (int m = 0; m < nt; m++) {
    tile_pid[toff + m] = lane;
    tile_tokoff[toff + m] = off + m * 128;
    tile_nrows[toff + m] = min(c - m * 128, 128);
  }
  if (lane == 63) meta[0] = toff + nt;
}

// ---------------- scatter tokens into pair-group lists ----------------
__global__ void scatter_kernel(const int* __restrict__ pairs, const int* __restrict__ pair_off,
                               int* __restrict__ pair_fill, int* __restrict__ token_list) {
  int t = blockIdx.x * blockDim.x + threadIdx.x;
  if (t >= NTOK) return;
  int pid = pairs[t];
  int pos = atomicAdd(&pair_fill[pid], 1);
  token_list[pair_off[pid] + pos] = t;
}

// ---------------- grouped GEMM over expert pairs ----------------
// Block tile 128(tokens) x 256(cols), K = 4096 (W[e1] then W[e2]; A = [hs|hs]), BK = 64.
// 512 threads = 8 waves arranged 2(m) x 4(n); each wave owns a 64x64 quadrant (4x4 mfma
// 16x16x32). Fragment-major LDS: chunk = one 16x32 MFMA tile = 1 KB in lane order
// (lane L's 16B at chunk + L*16). A: 16 chunks (8 mtiles x 2 kk); B: 32 chunks
// (16 ntiles x 2 kk). Wave w stages A chunks {2w,2w+1} (= its 16 token rows, both kk)
// and B chunks {4w..4w+3}. All ds_read_b128 at base+lane*16: conflict-free.
__global__ __launch_bounds__(512, 4) void moe_gemm(
    const ushort_t* __restrict__ hsb, const ushort_t* __restrict__ Wb,
    const float* __restrict__ bias, const int* __restrict__ token_list,
    const int* __restrict__ meta, const int* __restrict__ tile_pid,
    const int* __restrict__ tile_tokoff, const int* __restrict__ tile_nrows,
    float* __restrict__ out)
{
  __shared__ ushort_t Als[16 * 512];   // 16 KB
  __shared__ ushort_t Bls[32 * 512];   // 32 KB
  __shared__ int toks[128];

  const int ntile = blockIdx.x & (NT - 1);
  const int btile = blockIdx.x >> 3;
  if (btile >= meta[0]) return;
  const int pid = tile_pid[btile];
  const int e1 = pid >> 3, e2 = pid & 7;
  const int tokoff = tile_tokoff[btile];
  const int nrows = tile_nrows[btile];
  const int n0 = ntile * 256;

  const int tid = threadIdx.x;
  if (tid < 128) toks[tid] = (tid < nrows) ? token_list[tokoff + tid] : -1;
  __syncthreads();

  const int lane = tid & 63;
  const int wave = tid >> 6;      // 0..7
  const int l15 = lane & 15;
  const int lhi = lane >> 4;      // 0..3

  // staging addresses for wave `wave`
  const int tokw = toks[wave * 16 + l15];
  const ushort_t* arow = hsb + (size_t)(tokw < 0 ? 0 : tokw) * DM + lhi * 8;  // pad rows -> row 0
  const size_t brow0 = (size_t)(n0 + wave * 32 + l15) * DM + lhi * 8;         // ni = 2w
  const size_t brow1 = brow0 + (size_t)16 * DM;                                // ni = 2w+1
  ushort_t* als = Als + wave * 1024;   // chunks 2w, 2w+1
  ushort_t* bls = Bls + wave * 2048;   // chunks 4w..4w+3

  f32x4 acc[4][4] = {};
  const size_t wstride = (size_t)DM * DM;
  const int miB = (wave >> 2) * 4;     // m-subtile base for compute
  const int niB = (wave & 3) * 4;      // n-subtile base for compute

  for (int k0 = 0; k0 < KTOT; k0 += 64) {
    const int ka = k0 & (DM - 1);      // A and B k-offsets both wrap at DM
    const ushort_t* wbase = Wb + (size_t)(k0 < DM ? e1 : e2) * wstride + ka;
    GLOAD_LDS16(arow + ka,        als);
    GLOAD_LDS16(arow + ka + 32,   als + 512);
    GLOAD_LDS16(wbase + brow0,      bls);
    GLOAD_LDS16(wbase + brow0 + 32, bls + 512);
    GLOAD_LDS16(wbase + brow1,      bls + 1024);
    GLOAD_LDS16(wbase + brow1 + 32, bls + 1536);
    __syncthreads();
#pragma unroll
    for (int kk = 0; kk < 2; kk++) {
      bf16x8 af[4], bfr[4];
#pragma unroll
      for (int i = 0; i < 4; i++)
        af[i] = *(const bf16x8*)(&Als[((miB + i) * 2 + kk) * 512 + lane * 8]);
#pragma unroll
      for (int j = 0; j < 4; j++)
        bfr[j] = *(const bf16x8*)(&Bls[((niB + j) * 2 + kk) * 512 + lane * 8]);
#pragma unroll
      for (int i = 0; i < 4; i++)
#pragma unroll
        for (int j = 0; j < 4; j++)
          acc[i][j] = __builtin_amdgcn_mfma_f32_16x16x32_bf16(af[i], bfr[j], acc[i][j], 0, 0, 0);
    }
    __syncthreads();
  }

  // epilogue: C/D layout col=lane&15, row=(lane>>4)*4+reg; one writer per element
  const int wm = (wave >> 2) * 64;
  const int wn = (wave & 3) * 64;
#pragma unroll
  for (int j = 0; j < 4; j++) {
    const int col = n0 + wn + j * 16 + l15;
    const float bsum = bias[e1 * DM + col] + bias[e2 * DM + col];
#pragma unroll
    for (int i = 0; i < 4; i++) {
      const int rbase = wm + i * 16 + lhi * 4;
#pragma unroll
      for (int r = 0; r < 4; r++) {
        const int tok = toks[rbase + r];
        if (tok >= 0) out[(size_t)tok * DM + col] = acc[i][j][r] + bsum;
      }
    }
  }
}

extern "C" void kernel_launch(void* const* d_in, const int* in_sizes, int n_in,
                              void* d_out, int out_size, void* d_ws, size_t ws_size,
                              hipStream_t stream) {
  const float* hs = (const float*)d_in[0];
  const float* Wg = (const float*)d_in[1];
  const float* bg = (const float*)d_in[2];
  const float* W  = (const float*)d_in[3];
  const float* b  = (const float*)d_in[4];
  float* out = (float*)d_out;

  char* ws = (char*)d_ws;
  int* pair_cnt    = (int*)(ws + 0);      // 64 ints
  int* pair_fill   = (int*)(ws + 256);    // 64 ints
  int* meta        = (int*)(ws + 512);    // 16 ints
  int* pair_off    = (int*)(ws + 576);    // 64 ints
  int* tile_pid    = (int*)(ws + 832);    // MAXT
  int* tile_tokoff = (int*)(ws + 1600);   // MAXT
  int* tile_nrows  = (int*)(ws + 2368);   // MAXT
  int* pairs       = (int*)(ws + 3136);   // 16384
  int* token_list  = (int*)(ws + 68672);  // 16384
  ushort_t* Wb  = (ushort_t*)(ws + 134400);              // 64 MiB
  ushort_t* hsb = (ushort_t*)(ws + 134400 + 67108864);   // 64 MiB

  hipMemsetAsync(d_ws, 0, 576, stream);   // pair_cnt + pair_fill + meta

  prep_kernel<<<8192 + 4096, 256, 0, stream>>>(W, Wb, hs, Wg, bg, pair_cnt, pairs, hsb);
  scan_kernel<<<1, 64, 0, stream>>>(pair_cnt, meta, pair_off, tile_pid, tile_tokoff, tile_nrows);
  scatter_kernel<<<NTOK / 256, 256, 0, stream>>>(pairs, pair_off, pair_fill, token_list);
  moe_gemm<<<MAXT * NT, 512, 0, stream>>>(hsb, Wb, b, token_list, meta,
                                          tile_pid, tile_tokoff, tile_nrows, out);
}